// Round 6
// baseline (237.836 us; speedup 1.0000x reference)
//
#include <hip/hip_runtime.h>
#include <stdint.h>

typedef _Float16 f16;
typedef _Float16 half8 __attribute__((ext_vector_type(8)));
typedef float f32x4 __attribute__((ext_vector_type(4)));

#define BATCH 16
#define NQ 64
#define SL 4096
#define DH 128

// Tiled f16 layout for Kt/Vt, per b (halves):
//   off(d, n) = (n>>5)*4096 + (d>>4)*512 + ((n>>3)&3)*128 + (d&15)*8 + (n&7)
// A fragment read (16x16x32 MFMA) is then LDS/global  base + lane*16 bytes.

typedef __attribute__((address_space(3))) uint8_t lds8_t;
typedef __attribute__((address_space(1))) uint8_t glb8_t;

__device__ __forceinline__ void gload16(const void* g, void* l) {
  __builtin_amdgcn_global_load_lds((const glb8_t*)g, (lds8_t*)l, 16, 0, 0);
}

// ---------------------------------------------------------------------------
// Kernel P: convert f32 [b][n][d] -> f16 tiled [b][(d,n) tiled]
// ---------------------------------------------------------------------------
__global__ __launch_bounds__(256) void kprep(const float* __restrict__ Kg,
                                             const float* __restrict__ Vg,
                                             f16* __restrict__ Kt,
                                             f16* __restrict__ Vt) {
  __shared__ f16 Ld[128][130];
  const int blk = blockIdx.x;
  const int b = blk >> 6;
  const int tensor = (blk >> 5) & 1;
  const int chunk = blk & 31;
  const float* src = tensor ? Vg : Kg;
  f16* dst = tensor ? Vt : Kt;
  const int t = threadIdx.x;
  const int n0 = chunk * 128;
  {
    const int d = t & 127;
    const int nl = t >> 7;  // 0..1
    const float* s = src + ((size_t)b * SL + n0 + nl) * DH + d;
    for (int it = 0; it < 64; ++it)
      Ld[d][nl + it * 2] = (f16)s[(size_t)it * 2 * DH];
  }
  __syncthreads();
  {
    const int r = t & 15;
    const int kc = (t >> 4) & 3;
    const int w = t >> 6;
    char* dstb = (char*)(dst + (size_t)b * DH * SL);
#pragma unroll
    for (int tl = 0; tl < 4; ++tl)
#pragma unroll
      for (int hh = 0; hh < 2; ++hh) {
        const int dhi = w + hh * 4;
        const int d = dhi * 16 + r;
        const int nl = tl * 32 + kc * 8;
        const half8 v = *(const half8*)&Ld[d][nl];
        *(half8*)(dstb + (size_t)(chunk * 4 + tl) * 8192 + dhi * 1024 +
                  kc * 256 + r * 16) = v;
      }
  }
}

// ---------------------------------------------------------------------------
// Kernel S: E[b][q][n] = (f16)exp(scale * Q.K[n]).  Reads tiled Kt.
// XCD-swizzled blockIdx (512 blocks, 64/XCD -> 2 b's per XCD L2).
// ---------------------------------------------------------------------------
__global__ __launch_bounds__(256) void kscore(const float* __restrict__ Q,
                                              const f16* __restrict__ Kt,
                                              f16* __restrict__ E) {
  const int blk = (blockIdx.x & 7) * 64 + (blockIdx.x >> 3);
  __shared__ float Qs[8][128];
  const int b = blk >> 5;
  const int qg = (blk >> 2) & 7;
  const int ns = blk & 3;
  const int t = threadIdx.x;
  for (int i = t; i < 8 * 128; i += 256)
    Qs[i >> 7][i & 127] = Q[((size_t)b * NQ + qg * 8 + (i >> 7)) * DH + (i & 127)];
  __syncthreads();
  const int w = t >> 6, l = t & 63;
  const int q0 = (w >> 1) * 4;
  const int nbase = ns * 1024 + (w & 1) * 512 + l * 8;
  const f16* kb = Kt + (size_t)b * DH * SL + (size_t)(nbase >> 5) * 4096 +
                  (size_t)((nbase >> 3) & 3) * 128;
  float acc[4][8] = {};
  for (int d = 0; d < DH; ++d) {
    const half8 kv = *(const half8*)(kb + (d >> 4) * 512 + (d & 15) * 8);
    float kf[8];
#pragma unroll
    for (int j = 0; j < 8; ++j) kf[j] = (float)kv[j];
#pragma unroll
    for (int qi = 0; qi < 4; ++qi) {
      const float qv = Qs[q0 + qi][d];
#pragma unroll
      for (int j = 0; j < 8; ++j) acc[qi][j] += qv * kf[j];
    }
  }
  const float scl = 0.08838834764831845f;  // 1/sqrt(128)
#pragma unroll
  for (int qi = 0; qi < 4; ++qi) {
    half8 ev;
#pragma unroll
    for (int j = 0; j < 8; ++j) ev[j] = (f16)__expf(acc[qi][j] * scl);
    *(half8*)&E[((size_t)b * NQ + qg * 8 + q0 + qi) * SL + nbase] = ev;
  }
}

// ---------------------------------------------------------------------------
// Kernel R: denom[b][q] = sum_n E[b][q][n] (f16 in, f32 acc, deterministic)
// ---------------------------------------------------------------------------
__global__ __launch_bounds__(256) void kreduce(const f16* __restrict__ E,
                                               float* __restrict__ denom) {
  const int gw = blockIdx.x * 4 + (threadIdx.x >> 6);
  const int lane = threadIdx.x & 63;
  const f16* e = E + (size_t)gw * SL;
  float s = 0.f;
#pragma unroll
  for (int i = 0; i < 8; ++i) {
    const half8 h = *(const half8*)(e + i * 512 + lane * 8);
#pragma unroll
    for (int j = 0; j < 8; ++j) s += (float)h[j];
  }
  for (int off = 1; off < 64; off <<= 1) s += __shfl_xor(s, off);
  if (lane == 0) denom[gw] = s;
}

// ---------------------------------------------------------------------------
// Kernel EVK: EVp[nh][b][q][v] = sum_{n in half} E*V (and EK) via MFMA.
// ---------------------------------------------------------------------------
__global__ __launch_bounds__(256) void kev(const f16* __restrict__ Vt,
                                           const f16* __restrict__ Kt,
                                           const f16* __restrict__ E,
                                           float* __restrict__ EVp,
                                           float* __restrict__ EKp) {
  const int blk = (blockIdx.x & 7) * 32 + (blockIdx.x >> 3);
  const int b = blk >> 4;
  const int tensor = (blk >> 3) & 1;
  const int qq = (blk >> 1) & 3;
  const int nh = blk & 1;
  const char* src = (const char*)((tensor ? Kt : Vt) + (size_t)b * DH * SL);
  float* dst = (tensor ? EKp : EVp) +
               ((size_t)nh * BATCH * NQ + (size_t)b * NQ + qq * 16) * DH;
  const f16* Eb = E + ((size_t)b * NQ + qq * 16) * SL;
  const int t = threadIdx.x, w = t >> 6, l = t & 63;
  f32x4 acc[2] = {};
  for (int n0 = nh * 2048; n0 < nh * 2048 + 2048; n0 += 32) {
    const half8 a0 =
        *(const half8*)(src + (size_t)(n0 >> 5) * 8192 + w * 1024 + l * 16);
    const half8 a1 =
        *(const half8*)(src + (size_t)(n0 >> 5) * 8192 + (w + 4) * 1024 + l * 16);
    const half8 b0 =
        *(const half8*)(Eb + (size_t)(l & 15) * SL + n0 + (l >> 4) * 8);
    acc[0] = __builtin_amdgcn_mfma_f32_16x16x32_f16(a0, b0, acc[0], 0, 0, 0);
    acc[1] = __builtin_amdgcn_mfma_f32_16x16x32_f16(a1, b0, acc[1], 0, 0, 0);
  }
#pragma unroll
  for (int sv2 = 0; sv2 < 2; ++sv2) {
    const int q = l & 15;
    const int row = (w + sv2 * 4) * 16 + (l >> 4) * 4;
    *(f32x4*)&dst[(size_t)q * DH + row] = acc[sv2];
  }
}

// ---------------------------------------------------------------------------
// Kernel G: per (b, 2 q):  T[v][k] = sum_n (E_n*V[n,v]) * K[n,k]  via MFMA.
// 512 thr / 8 waves; wave = 64x32 quadrant for both q (acc 64 AGPR).
// Single barrier per tile; ds_read of tile t+1 overlaps MFMA(t) via dual
// frag sets; 4 LDS buffers, stage dist 3, counted vmcnt (never 0 in loop).
// ---------------------------------------------------------------------------
__global__ __launch_bounds__(512, 2) void kjac(
    const f16* __restrict__ Vt, const f16* __restrict__ Kt,
    const f16* __restrict__ E, const float* __restrict__ EV,
    const float* __restrict__ EK, const float* __restrict__ denom,
    float* __restrict__ out) {
  __shared__ __align__(16) f16 Vl[4][4096];
  __shared__ __align__(16) f16 Kl[4][4096];

  const int blk = (blockIdx.x & 7) * 64 + (blockIdx.x >> 3);  // XCD swizzle
  const int b = blk >> 5;
  const int q0 = (blk & 31) * 2;
  const int t = threadIdx.x, w = t >> 6, l = t & 63;
  const int rh = w >> 2;  // row half: 64 v-rows
  const int cq = w & 3;   // col quarter: 32 k-cols
  const char* vtb = (const char*)(Vt + (size_t)b * DH * SL);
  const char* ktb = (const char*)(Kt + (size_t)b * DH * SL);
  const f16* Eb = E + ((size_t)b * NQ + q0) * SL;

  f32x4 acc[2][4][2] = {};
  half8 vfA[4], kfA[2], vfB[4], kfB[2], eA[2], eB[2];

  // stage: 16KB/tile, 512 thr -> 2 gload16 each
#define STAGE(tile)                                                          \
  {                                                                          \
    const size_t gb = (size_t)(tile) * 8192 + t * 16;                        \
    const int bi = (tile) & 3;                                               \
    gload16(vtb + gb, (char*)Vl[bi] + t * 16);                               \
    gload16(ktb + gb, (char*)Kl[bi] + t * 16);                               \
  }

#define ELOAD(e, tile)                                                       \
  {                                                                          \
    const int nn = (tile) * 32 + (l >> 4) * 8;                               \
    e[0] = *(const half8*)(Eb + nn);                                         \
    e[1] = *(const half8*)(Eb + SL + nn);                                    \
  }

#define FLOAD(vf, kf, tile)                                                  \
  {                                                                          \
    const f16* vbuf = Vl[(tile) & 3];                                        \
    const f16* kbuf = Kl[(tile) & 3];                                        \
    _Pragma("unroll") for (int i = 0; i < 4; ++i) vf[i] =                    \
        *(const half8*)(vbuf + (rh * 4 + i) * 512 + l * 8);                  \
    _Pragma("unroll") for (int j = 0; j < 2; ++j) kf[j] =                    \
        *(const half8*)(kbuf + (cq * 2 + j) * 512 + l * 8);                  \
  }

#define MFMA8(vf, kf, e)                                                     \
  {                                                                          \
    __builtin_amdgcn_s_setprio(1);                                           \
    _Pragma("unroll") for (int i = 0; i < 4; ++i) {                          \
      const half8 u0 = e[0] * vf[i];                                         \
      const half8 u1 = e[1] * vf[i];                                         \
      _Pragma("unroll") for (int j = 0; j < 2; ++j) {                        \
        acc[0][i][j] = __builtin_amdgcn_mfma_f32_16x16x32_f16(               \
            u0, kf[j], acc[0][i][j], 0, 0, 0);                               \
        acc[1][i][j] = __builtin_amdgcn_mfma_f32_16x16x32_f16(               \
            u1, kf[j], acc[1][i][j], 0, 0, 0);                               \
      }                                                                      \
    }                                                                        \
    __builtin_amdgcn_s_setprio(0);                                           \
  }

  // phase TC: barrier+counted vmcnt; prefetch e/frags of TC+1; stage TC+3;
  // MFMA on TC (overlaps the just-issued ds_reads).
#define PHASE(TC, CVF, CKF, CE, NVF, NKF, NE, VM, DOST)                      \
  {                                                                          \
    asm volatile("s_waitcnt vmcnt(" #VM ")\n\ts_barrier" ::: "memory");      \
    ELOAD(NE, (TC) + 1)                                                      \
    FLOAD(NVF, NKF, (TC) + 1)                                                \
    if (DOST) STAGE((TC) + 3)                                                \
    MFMA8(CVF, CKF, CE)                                                      \
  }

  ELOAD(eA, 0)
  STAGE(0) STAGE(1) STAGE(2)
  // queue: e0(2) s0(2) s1(2) s2(2); need s0 done -> vmcnt(4)
  asm volatile("s_waitcnt vmcnt(4)\n\ts_barrier" ::: "memory");
  FLOAD(vfA, kfA, 0)
  // phase0: outstanding s1(2) s2(2); need s1 -> vmcnt(2)
  PHASE(0, vfA, kfA, eA, vfB, kfB, eB, 2, 1)
  // steady: outstanding s(t+1)2 e(t)2 s(t+2)2 = 6; need s(t+1) -> vmcnt(4)
  for (int tt = 1; tt < 125; tt += 2) {
    PHASE(tt, vfB, kfB, eB, vfA, kfA, eA, 4, 1)
    PHASE(tt + 1, vfA, kfA, eA, vfB, kfB, eB, 4, 1)
  }
  PHASE(125, vfB, kfB, eB, vfA, kfA, eA, 4, 0)
  // ph126: outstanding s127(2) e126(2); need s127 -> vmcnt(2)
  PHASE(126, vfA, kfA, eA, vfB, kfB, eB, 2, 0)
  MFMA8(vfB, kfB, eB)  // compiler waits e127 itself
#undef STAGE
#undef ELOAD
#undef FLOAD
#undef MFMA8
#undef PHASE

  const float scl = 0.08838834764831845f;
#pragma unroll
  for (int q = 0; q < 2; ++q) {
    const float invd = 1.0f / denom[b * NQ + q0 + q];
    const float* evq = EV + ((size_t)b * NQ + q0 + q) * DH;
    const float* evq2 = evq + (size_t)BATCH * NQ * DH;
    const float* ekq = EK + ((size_t)b * NQ + q0 + q) * DH;
    const float* ekq2 = ekq + (size_t)BATCH * NQ * DH;
    float* ob = out + (size_t)(b * NQ + q0 + q) * DH * DH;
#pragma unroll
    for (int i = 0; i < 4; ++i) {
      const int row0 = rh * 64 + i * 16 + (l >> 4) * 4;
      const f32x4 ev4 = *(const f32x4*)&evq[row0] + *(const f32x4*)&evq2[row0];
#pragma unroll
      for (int j = 0; j < 2; ++j) {
        const int col = cq * 32 + j * 16 + (l & 15);
        const float ek = ekq[col] + ekq2[col];
#pragma unroll
        for (int r = 0; r < 4; ++r)
          ob[(size_t)(row0 + r) * DH + col] =
              scl * invd * (acc[q][i][j][r] - invd * ev4[r] * ek);
      }
    }
  }
}

extern "C" void kernel_launch(void* const* d_in, const int* in_sizes, int n_in,
                              void* d_out, int out_size, void* d_ws,
                              size_t ws_size, hipStream_t stream) {
  const float* Q = (const float*)d_in[0];
  const float* K = (const float*)d_in[1];
  const float* V = (const float*)d_in[2];
  float* out = (float*)d_out;

  // ws: Vt 16.8MB | Kt 16.8MB | E f16 8.4MB | EVp 1MB | EKp 1MB | denom 4KB
  f16* Vt = (f16*)d_ws;
  f16* Kt = Vt + (size_t)BATCH * DH * SL;
  f16* Ef = Kt + (size_t)BATCH * DH * SL;
  float* EV = (float*)(Ef + (size_t)BATCH * NQ * SL);
  float* EK = EV + 2 * (size_t)BATCH * NQ * DH;
  float* denom = EK + 2 * (size_t)BATCH * NQ * DH;

  kprep<<<1024, 256, 0, stream>>>(K, V, Kt, Vt);
  kscore<<<512, 256, 0, stream>>>(Q, Kt, Ef);
  kreduce<<<256, 256, 0, stream>>>(Ef, denom);
  kev<<<256, 256, 0, stream>>>(Vt, Kt, Ef, EV, EK);
  kjac<<<512, 512, 0, stream>>>(Vt, Kt, Ef, EV, EK, denom, out);
}

// Round 7
// 193.586 us; speedup vs baseline: 1.2286x; 1.2286x over previous
//
#include <hip/hip_runtime.h>
#include <stdint.h>

typedef _Float16 f16;
typedef _Float16 half8 __attribute__((ext_vector_type(8)));
typedef float f32x4 __attribute__((ext_vector_type(4)));

#define BATCH 16
#define NQ 64
#define SL 4096
#define DH 128

// Tiled f16 layout for Kt/Vt, per b (halves):
//   off(d, n) = (n>>5)*4096 + (d>>4)*512 + ((n>>3)&3)*128 + (d&15)*8 + (n&7)
// A fragment read (16x16x32 MFMA) is then LDS/global  base + lane*16 bytes.

typedef __attribute__((address_space(3))) uint8_t lds8_t;
typedef __attribute__((address_space(1))) uint8_t glb8_t;

__device__ __forceinline__ void gload16(const void* g, void* l) {
  __builtin_amdgcn_global_load_lds((const glb8_t*)g, (lds8_t*)l, 16, 0, 0);
}

// ---------------------------------------------------------------------------
// Kernel P: convert f32 [b][n][d] -> f16 tiled [b][(d,n) tiled]
// ---------------------------------------------------------------------------
__global__ __launch_bounds__(256) void kprep(const float* __restrict__ Kg,
                                             const float* __restrict__ Vg,
                                             f16* __restrict__ Kt,
                                             f16* __restrict__ Vt) {
  __shared__ f16 Ld[128][130];
  const int blk = blockIdx.x;
  const int b = blk >> 6;
  const int tensor = (blk >> 5) & 1;
  const int chunk = blk & 31;
  const float* src = tensor ? Vg : Kg;
  f16* dst = tensor ? Vt : Kt;
  const int t = threadIdx.x;
  const int n0 = chunk * 128;
  {
    const int d = t & 127;
    const int nl = t >> 7;  // 0..1
    const float* s = src + ((size_t)b * SL + n0 + nl) * DH + d;
    for (int it = 0; it < 64; ++it)
      Ld[d][nl + it * 2] = (f16)s[(size_t)it * 2 * DH];
  }
  __syncthreads();
  {
    const int r = t & 15;
    const int kc = (t >> 4) & 3;
    const int w = t >> 6;
    char* dstb = (char*)(dst + (size_t)b * DH * SL);
#pragma unroll
    for (int tl = 0; tl < 4; ++tl)
#pragma unroll
      for (int hh = 0; hh < 2; ++hh) {
        const int dhi = w + hh * 4;
        const int d = dhi * 16 + r;
        const int nl = tl * 32 + kc * 8;
        const half8 v = *(const half8*)&Ld[d][nl];
        *(half8*)(dstb + (size_t)(chunk * 4 + tl) * 8192 + dhi * 1024 +
                  kc * 256 + r * 16) = v;
      }
  }
}

// ---------------------------------------------------------------------------
// Kernel S: E[b][q][n] = (f16)exp(scale * Q.K[n]).  Reads tiled Kt.
// ---------------------------------------------------------------------------
__global__ __launch_bounds__(256) void kscore(const float* __restrict__ Q,
                                              const f16* __restrict__ Kt,
                                              f16* __restrict__ E) {
  const int blk = (blockIdx.x & 7) * 64 + (blockIdx.x >> 3);
  __shared__ float Qs[8][128];
  const int b = blk >> 5;
  const int qg = (blk >> 2) & 7;
  const int ns = blk & 3;
  const int t = threadIdx.x;
  for (int i = t; i < 8 * 128; i += 256)
    Qs[i >> 7][i & 127] = Q[((size_t)b * NQ + qg * 8 + (i >> 7)) * DH + (i & 127)];
  __syncthreads();
  const int w = t >> 6, l = t & 63;
  const int q0 = (w >> 1) * 4;
  const int nbase = ns * 1024 + (w & 1) * 512 + l * 8;
  const f16* kb = Kt + (size_t)b * DH * SL + (size_t)(nbase >> 5) * 4096 +
                  (size_t)((nbase >> 3) & 3) * 128;
  float acc[4][8] = {};
  for (int d = 0; d < DH; ++d) {
    const half8 kv = *(const half8*)(kb + (d >> 4) * 512 + (d & 15) * 8);
    float kf[8];
#pragma unroll
    for (int j = 0; j < 8; ++j) kf[j] = (float)kv[j];
#pragma unroll
    for (int qi = 0; qi < 4; ++qi) {
      const float qv = Qs[q0 + qi][d];
#pragma unroll
      for (int j = 0; j < 8; ++j) acc[qi][j] += qv * kf[j];
    }
  }
  const float scl = 0.08838834764831845f;  // 1/sqrt(128)
#pragma unroll
  for (int qi = 0; qi < 4; ++qi) {
    half8 ev;
#pragma unroll
    for (int j = 0; j < 8; ++j) ev[j] = (f16)__expf(acc[qi][j] * scl);
    *(half8*)&E[((size_t)b * NQ + qg * 8 + q0 + qi) * SL + nbase] = ev;
  }
}

// ---------------------------------------------------------------------------
// Kernel R: denom[b][q] = sum_n E[b][q][n] (f16 in, f32 acc, deterministic)
// ---------------------------------------------------------------------------
__global__ __launch_bounds__(256) void kreduce(const f16* __restrict__ E,
                                               float* __restrict__ denom) {
  const int gw = blockIdx.x * 4 + (threadIdx.x >> 6);
  const int lane = threadIdx.x & 63;
  const f16* e = E + (size_t)gw * SL;
  float s = 0.f;
#pragma unroll
  for (int i = 0; i < 8; ++i) {
    const half8 h = *(const half8*)(e + i * 512 + lane * 8);
#pragma unroll
    for (int j = 0; j < 8; ++j) s += (float)h[j];
  }
  for (int off = 1; off < 64; off <<= 1) s += __shfl_xor(s, off);
  if (lane == 0) denom[gw] = s;
}

// ---------------------------------------------------------------------------
// Kernel EVK: EVp[nh][b][q][v] = sum_{n in half} E*V (and EK) via MFMA.
// ---------------------------------------------------------------------------
__global__ __launch_bounds__(256) void kev(const f16* __restrict__ Vt,
                                           const f16* __restrict__ Kt,
                                           const f16* __restrict__ E,
                                           float* __restrict__ EVp,
                                           float* __restrict__ EKp) {
  const int blk = (blockIdx.x & 7) * 32 + (blockIdx.x >> 3);
  const int b = blk >> 4;
  const int tensor = (blk >> 3) & 1;
  const int qq = (blk >> 1) & 3;
  const int nh = blk & 1;
  const char* src = (const char*)((tensor ? Kt : Vt) + (size_t)b * DH * SL);
  float* dst = (tensor ? EKp : EVp) +
               ((size_t)nh * BATCH * NQ + (size_t)b * NQ + qq * 16) * DH;
  const f16* Eb = E + ((size_t)b * NQ + qq * 16) * SL;
  const int t = threadIdx.x, w = t >> 6, l = t & 63;
  f32x4 acc[2] = {};
  for (int n0 = nh * 2048; n0 < nh * 2048 + 2048; n0 += 32) {
    const half8 a0 =
        *(const half8*)(src + (size_t)(n0 >> 5) * 8192 + w * 1024 + l * 16);
    const half8 a1 =
        *(const half8*)(src + (size_t)(n0 >> 5) * 8192 + (w + 4) * 1024 + l * 16);
    const half8 b0 =
        *(const half8*)(Eb + (size_t)(l & 15) * SL + n0 + (l >> 4) * 8);
    acc[0] = __builtin_amdgcn_mfma_f32_16x16x32_f16(a0, b0, acc[0], 0, 0, 0);
    acc[1] = __builtin_amdgcn_mfma_f32_16x16x32_f16(a1, b0, acc[1], 0, 0, 0);
  }
#pragma unroll
  for (int sv2 = 0; sv2 < 2; ++sv2) {
    const int q = l & 15;
    const int row = (w + sv2 * 4) * 16 + (l >> 4) * 4;
    *(f32x4*)&dst[(size_t)q * DH + row] = acc[sv2];
  }
}

// ---------------------------------------------------------------------------
// Kernel G: per (b, 2 q):  T[v][k] = sum_n (E_n*V[n,v]) * K[n,k]  via MFMA.
// 256 thr / 4 waves (64x64 quadrant per wave).  ONE barrier per tile:
// FLOAD/ELOAD(t+1) + STAGE(t+3) overlap MFMA(t).  All loop VMEM ops are
// global_load_lds (E staged through LDS too) so the counted vmcnt ladder
// is never drained by compiler-inserted waits.  4-buffer V/K ring, E in
// 2x4KB chunk buffers (32 tiles each).
// ---------------------------------------------------------------------------
__global__ __launch_bounds__(256, 2) void kjac(
    const f16* __restrict__ Vt, const f16* __restrict__ Kt,
    const f16* __restrict__ E, const float* __restrict__ EV,
    const float* __restrict__ EK, const float* __restrict__ denom,
    float* __restrict__ out) {
  __shared__ __align__(16) f16 Vl[4][4096];
  __shared__ __align__(16) f16 Kl[4][4096];
  __shared__ __align__(16) f16 El[2][2048];  // [chunk&1][q*1024 + n]

  const int blk = (blockIdx.x & 7) * 64 + (blockIdx.x >> 3);  // XCD swizzle
  const int b = blk >> 5;
  const int q0 = (blk & 31) * 2;
  const int t = threadIdx.x, w = t >> 6, l = t & 63;
  const int sA = (w >> 1) * 4;  // A row-subtile base (quadrant)
  const int sB = (w & 1) * 4;   // B col-subtile base
  const char* vtb = (const char*)(Vt + (size_t)b * DH * SL);
  const char* ktb = (const char*)(Kt + (size_t)b * DH * SL);
  const f16* Eb = E + ((size_t)b * NQ + q0) * SL;

  f32x4 acc[2][4][4] = {};
  half8 vf[2][4], kf[2][4], ef[2][2];

#define STAGE(tile, bi)                                                      \
  {                                                                          \
    const size_t gb = (size_t)(tile) * 8192 + t * 16;                        \
    gload16(vtb + gb, (char*)Vl[bi] + t * 16);                               \
    gload16(vtb + gb + 4096, (char*)Vl[bi] + t * 16 + 4096);                 \
    gload16(ktb + gb, (char*)Kl[bi] + t * 16);                               \
    gload16(ktb + gb + 4096, (char*)Kl[bi] + t * 16 + 4096);                 \
  }

  // E chunk c covers tiles [32c, 32c+32): 2 q-rows x 1024 halves = 4KB
#define ESTAGE(c)                                                            \
  {                                                                          \
    const char* esrc = (const char*)(Eb + ((t >> 7) ? SL : 0) +              \
                                     (size_t)(c) * 1024) + (t & 127) * 16;   \
    gload16(esrc, (char*)El[(c) & 1] + t * 16);                              \
  }

#define ELOADDS(dst, elbase, nk)                                             \
  {                                                                          \
    dst[0] = *(const half8*)((elbase) + (nk) * 32 + (l >> 4) * 8);           \
    dst[1] = *(const half8*)((elbase) + 1024 + (nk) * 32 + (l >> 4) * 8);    \
  }

#define FLOAD(vv, kk, bi)                                                    \
  {                                                                          \
    _Pragma("unroll") for (int i = 0; i < 4; ++i) vv[i] =                    \
        *(const half8*)(Vl[bi] + (sA + i) * 512 + l * 8);                    \
    _Pragma("unroll") for (int j = 0; j < 4; ++j) kk[j] =                    \
        *(const half8*)(Kl[bi] + (sB + j) * 512 + l * 8);                    \
  }

#define MFMA32(s)                                                            \
  {                                                                          \
    __builtin_amdgcn_s_setprio(1);                                           \
    _Pragma("unroll") for (int i = 0; i < 4; ++i) {                          \
      const half8 u0 = ef[s][0] * vf[s][i];                                  \
      const half8 u1 = ef[s][1] * vf[s][i];                                  \
      _Pragma("unroll") for (int j = 0; j < 4; ++j) {                        \
        acc[0][i][j] = __builtin_amdgcn_mfma_f32_16x16x32_f16(               \
            u0, kf[s][j], acc[0][i][j], 0, 0, 0);                            \
        acc[1][i][j] = __builtin_amdgcn_mfma_f32_16x16x32_f16(               \
            u1, kf[s][j], acc[1][i][j], 0, 0, 0);                            \
      }                                                                      \
    }                                                                        \
    __builtin_amdgcn_s_setprio(0);                                           \
  }

#define VMB(N)                                                               \
  asm volatile("s_waitcnt vmcnt(" #N ")\n\ts_barrier" ::: "memory");

  // ---- prologue: stage E chunk 0 + tiles 0..2, drain once ----
  ESTAGE(0)
  STAGE(0, 0) STAGE(1, 1) STAGE(2, 2)
  VMB(0)
  FLOAD(vf[0], kf[0], 0)
  ELOADDS(ef[0], El[0], 0)

  for (int g = 0; g < 3; ++g) {
    const f16* elc = El[g & 1];
    const f16* eln = El[(g + 1) & 1];
    const int tb = g * 32;
    // k=0: also stage next E chunk
    VMB(4) FLOAD(vf[1], kf[1], 1) ELOADDS(ef[1], elc, 1)
    STAGE(tb + 3, 3) ESTAGE(g + 1) MFMA32(0)
    // k=1 (E-stage in vmcnt window)
    VMB(5) FLOAD(vf[0], kf[0], 2) ELOADDS(ef[0], elc, 2) STAGE(tb + 4, 0) MFMA32(1)
    // k=2
    VMB(4) FLOAD(vf[1], kf[1], 3) ELOADDS(ef[1], elc, 3) STAGE(tb + 5, 1) MFMA32(0)
    // k=3
    VMB(4) FLOAD(vf[0], kf[0], 0) ELOADDS(ef[0], elc, 4) STAGE(tb + 6, 2) MFMA32(1)
    for (int kk = 4; kk < 28; kk += 4) {
      VMB(4) FLOAD(vf[1], kf[1], 1) ELOADDS(ef[1], elc, kk + 1)
      STAGE(tb + kk + 3, 3) MFMA32(0)
      VMB(4) FLOAD(vf[0], kf[0], 2) ELOADDS(ef[0], elc, kk + 2)
      STAGE(tb + kk + 4, 0) MFMA32(1)
      VMB(4) FLOAD(vf[1], kf[1], 3) ELOADDS(ef[1], elc, kk + 3)
      STAGE(tb + kk + 5, 1) MFMA32(0)
      VMB(4) FLOAD(vf[0], kf[0], 0) ELOADDS(ef[0], elc, kk + 4)
      STAGE(tb + kk + 6, 2) MFMA32(1)
    }
    // k=28..31 (k=31 preloads first tile of next chunk from eln)
    VMB(4) FLOAD(vf[1], kf[1], 1) ELOADDS(ef[1], elc, 29) STAGE(tb + 31, 3) MFMA32(0)
    VMB(4) FLOAD(vf[0], kf[0], 2) ELOADDS(ef[0], elc, 30) STAGE(tb + 32, 0) MFMA32(1)
    VMB(4) FLOAD(vf[1], kf[1], 3) ELOADDS(ef[1], elc, 31) STAGE(tb + 33, 1) MFMA32(0)
    VMB(4) FLOAD(vf[0], kf[0], 0) ELOADDS(ef[0], eln, 0) STAGE(tb + 34, 2) MFMA32(1)
  }
  // ---- tail group: tiles 96..127 (E chunk 3 in El[1]) ----
  {
    const f16* elc = El[1];
    VMB(4) FLOAD(vf[1], kf[1], 1) ELOADDS(ef[1], elc, 1) STAGE(99, 3) MFMA32(0)
    VMB(4) FLOAD(vf[0], kf[0], 2) ELOADDS(ef[0], elc, 2) STAGE(100, 0) MFMA32(1)
    VMB(4) FLOAD(vf[1], kf[1], 3) ELOADDS(ef[1], elc, 3) STAGE(101, 1) MFMA32(0)
    VMB(4) FLOAD(vf[0], kf[0], 0) ELOADDS(ef[0], elc, 4) STAGE(102, 2) MFMA32(1)
    for (int kk = 4; kk < 28; kk += 4) {
      VMB(4) FLOAD(vf[1], kf[1], 1) ELOADDS(ef[1], elc, kk + 1)
      STAGE(96 + kk + 3, 3) MFMA32(0)
      VMB(4) FLOAD(vf[0], kf[0], 2) ELOADDS(ef[0], elc, kk + 2)
      STAGE(96 + kk + 4, 0) MFMA32(1)
      VMB(4) FLOAD(vf[1], kf[1], 3) ELOADDS(ef[1], elc, kk + 3)
      STAGE(96 + kk + 5, 1) MFMA32(0)
      VMB(4) FLOAD(vf[0], kf[0], 0) ELOADDS(ef[0], elc, kk + 4)
      STAGE(96 + kk + 6, 2) MFMA32(1)
    }
    // k=28: stages last tile 127
    VMB(4) FLOAD(vf[1], kf[1], 1) ELOADDS(ef[1], elc, 29) STAGE(127, 3) MFMA32(0)
    // k=29..31: drain tail
    VMB(4) FLOAD(vf[0], kf[0], 2) ELOADDS(ef[0], elc, 30) MFMA32(1)
    VMB(0) FLOAD(vf[1], kf[1], 3) ELOADDS(ef[1], elc, 31) MFMA32(0)
    VMB(0) MFMA32(1)
  }
#undef STAGE
#undef ESTAGE
#undef ELOADDS
#undef FLOAD
#undef MFMA32
#undef VMB

  const float scl = 0.08838834764831845f;
#pragma unroll
  for (int q = 0; q < 2; ++q) {
    const float invd = 1.0f / denom[b * NQ + q0 + q];
    const float* evq = EV + ((size_t)b * NQ + q0 + q) * DH;
    const float* evq2 = evq + (size_t)BATCH * NQ * DH;
    const float* ekq = EK + ((size_t)b * NQ + q0 + q) * DH;
    const float* ekq2 = ekq + (size_t)BATCH * NQ * DH;
    float* ob = out + (size_t)(b * NQ + q0 + q) * DH * DH;
#pragma unroll
    for (int i = 0; i < 4; ++i) {
      const int row0 = (sA + i) * 16 + (l >> 4) * 4;
      const f32x4 ev4 = *(const f32x4*)&evq[row0] + *(const f32x4*)&evq2[row0];
#pragma unroll
      for (int j = 0; j < 4; ++j) {
        const int col = (sB + j) * 16 + (l & 15);
        const float ek = ekq[col] + ekq2[col];
#pragma unroll
        for (int r = 0; r < 4; ++r)
          ob[(size_t)(row0 + r) * DH + col] =
              scl * invd * (acc[q][i][j][r] - invd * ev4[r] * ek);
      }
    }
  }
}

extern "C" void kernel_launch(void* const* d_in, const int* in_sizes, int n_in,
                              void* d_out, int out_size, void* d_ws,
                              size_t ws_size, hipStream_t stream) {
  const float* Q = (const float*)d_in[0];
  const float* K = (const float*)d_in[1];
  const float* V = (const float*)d_in[2];
  float* out = (float*)d_out;

  // ws: Vt 16.8MB | Kt 16.8MB | E f16 8.4MB | EVp 1MB | EKp 1MB | denom 4KB
  f16* Vt = (f16*)d_ws;
  f16* Kt = Vt + (size_t)BATCH * DH * SL;
  f16* Ef = Kt + (size_t)BATCH * DH * SL;
  float* EV = (float*)(Ef + (size_t)BATCH * NQ * SL);
  float* EK = EV + 2 * (size_t)BATCH * NQ * DH;
  float* denom = EK + 2 * (size_t)BATCH * NQ * DH;

  kprep<<<1024, 256, 0, stream>>>(K, V, Kt, Vt);
  kscore<<<512, 256, 0, stream>>>(Q, Kt, Ef);
  kreduce<<<256, 256, 0, stream>>>(Ef, denom);
  kev<<<256, 256, 0, stream>>>(Vt, Kt, Ef, EV, EK);
  kjac<<<512, 256, 0, stream>>>(Vt, Kt, Ef, EV, EK, denom, out);
}

// Round 8
// 185.906 us; speedup vs baseline: 1.2793x; 1.0413x over previous
//
#include <hip/hip_runtime.h>
#include <stdint.h>

typedef _Float16 f16;
typedef _Float16 half8 __attribute__((ext_vector_type(8)));
typedef float f32x4 __attribute__((ext_vector_type(4)));

#define BATCH 16
#define NQ 64
#define SL 4096
#define DH 128

// Tiled f16 layout for Kt/Vt, per b (halves):
//   off(d, n) = (n>>5)*4096 + (d>>4)*512 + ((n>>3)&3)*128 + (d&15)*8 + (n&7)
// A fragment read (16x16x32 MFMA) is then a coalesced global read base+l*16.

// ---------------------------------------------------------------------------
// Kernel P: convert f32 [b][n][d] -> f16 tiled [b][(d,n) tiled]
// ---------------------------------------------------------------------------
__global__ __launch_bounds__(256) void kprep(const float* __restrict__ Kg,
                                             const float* __restrict__ Vg,
                                             f16* __restrict__ Kt,
                                             f16* __restrict__ Vt) {
  __shared__ f16 Ld[128][130];
  const int blk = blockIdx.x;
  const int b = blk >> 6;
  const int tensor = (blk >> 5) & 1;
  const int chunk = blk & 31;
  const float* src = tensor ? Vg : Kg;
  f16* dst = tensor ? Vt : Kt;
  const int t = threadIdx.x;
  const int n0 = chunk * 128;
  {
    const int d = t & 127;
    const int nl = t >> 7;  // 0..1
    const float* s = src + ((size_t)b * SL + n0 + nl) * DH + d;
    for (int it = 0; it < 64; ++it)
      Ld[d][nl + it * 2] = (f16)s[(size_t)it * 2 * DH];
  }
  __syncthreads();
  {
    const int r = t & 15;
    const int kc = (t >> 4) & 3;
    const int w = t >> 6;
    char* dstb = (char*)(dst + (size_t)b * DH * SL);
#pragma unroll
    for (int tl = 0; tl < 4; ++tl)
#pragma unroll
      for (int hh = 0; hh < 2; ++hh) {
        const int dhi = w + hh * 4;
        const int d = dhi * 16 + r;
        const int nl = tl * 32 + kc * 8;
        const half8 v = *(const half8*)&Ld[d][nl];
        *(half8*)(dstb + (size_t)(chunk * 4 + tl) * 8192 + dhi * 1024 +
                  kc * 256 + r * 16) = v;
      }
  }
}

// ---------------------------------------------------------------------------
// Kernel S: E[b][q][n] = (f16)exp(scale * Q.K[n]).  Reads tiled Kt.
// ---------------------------------------------------------------------------
__global__ __launch_bounds__(256) void kscore(const float* __restrict__ Q,
                                              const f16* __restrict__ Kt,
                                              f16* __restrict__ E) {
  const int blk = (blockIdx.x & 7) * 64 + (blockIdx.x >> 3);
  __shared__ float Qs[8][128];
  const int b = blk >> 5;
  const int qg = (blk >> 2) & 7;
  const int ns = blk & 3;
  const int t = threadIdx.x;
  for (int i = t; i < 8 * 128; i += 256)
    Qs[i >> 7][i & 127] = Q[((size_t)b * NQ + qg * 8 + (i >> 7)) * DH + (i & 127)];
  __syncthreads();
  const int w = t >> 6, l = t & 63;
  const int q0 = (w >> 1) * 4;
  const int nbase = ns * 1024 + (w & 1) * 512 + l * 8;
  const f16* kb = Kt + (size_t)b * DH * SL + (size_t)(nbase >> 5) * 4096 +
                  (size_t)((nbase >> 3) & 3) * 128;
  float acc[4][8] = {};
  for (int d = 0; d < DH; ++d) {
    const half8 kv = *(const half8*)(kb + (d >> 4) * 512 + (d & 15) * 8);
    float kf[8];
#pragma unroll
    for (int j = 0; j < 8; ++j) kf[j] = (float)kv[j];
#pragma unroll
    for (int qi = 0; qi < 4; ++qi) {
      const float qv = Qs[q0 + qi][d];
#pragma unroll
      for (int j = 0; j < 8; ++j) acc[qi][j] += qv * kf[j];
    }
  }
  const float scl = 0.08838834764831845f;  // 1/sqrt(128)
#pragma unroll
  for (int qi = 0; qi < 4; ++qi) {
    half8 ev;
#pragma unroll
    for (int j = 0; j < 8; ++j) ev[j] = (f16)__expf(acc[qi][j] * scl);
    *(half8*)&E[((size_t)b * NQ + qg * 8 + q0 + qi) * SL + nbase] = ev;
  }
}

// ---------------------------------------------------------------------------
// Kernel R: denom[b][q] = sum_n E[b][q][n] (f16 in, f32 acc, deterministic)
// ---------------------------------------------------------------------------
__global__ __launch_bounds__(256) void kreduce(const f16* __restrict__ E,
                                               float* __restrict__ denom) {
  const int gw = blockIdx.x * 4 + (threadIdx.x >> 6);
  const int lane = threadIdx.x & 63;
  const f16* e = E + (size_t)gw * SL;
  float s = 0.f;
#pragma unroll
  for (int i = 0; i < 8; ++i) {
    const half8 h = *(const half8*)(e + i * 512 + lane * 8);
#pragma unroll
    for (int j = 0; j < 8; ++j) s += (float)h[j];
  }
  for (int off = 1; off < 64; off <<= 1) s += __shfl_xor(s, off);
  if (lane == 0) denom[gw] = s;
}

// ---------------------------------------------------------------------------
// Kernel EVK: EVp[nh][b][q][v] = sum_{n in half} E*V (and EK) via MFMA.
// ---------------------------------------------------------------------------
__global__ __launch_bounds__(256) void kev(const f16* __restrict__ Vt,
                                           const f16* __restrict__ Kt,
                                           const f16* __restrict__ E,
                                           float* __restrict__ EVp,
                                           float* __restrict__ EKp) {
  const int blk = (blockIdx.x & 7) * 32 + (blockIdx.x >> 3);
  const int b = blk >> 4;
  const int tensor = (blk >> 3) & 1;
  const int qq = (blk >> 1) & 3;
  const int nh = blk & 1;
  const char* src = (const char*)((tensor ? Kt : Vt) + (size_t)b * DH * SL);
  float* dst = (tensor ? EKp : EVp) +
               ((size_t)nh * BATCH * NQ + (size_t)b * NQ + qq * 16) * DH;
  const f16* Eb = E + ((size_t)b * NQ + qq * 16) * SL;
  const int t = threadIdx.x, w = t >> 6, l = t & 63;
  f32x4 acc[2] = {};
  for (int n0 = nh * 2048; n0 < nh * 2048 + 2048; n0 += 32) {
    const half8 a0 =
        *(const half8*)(src + (size_t)(n0 >> 5) * 8192 + w * 1024 + l * 16);
    const half8 a1 =
        *(const half8*)(src + (size_t)(n0 >> 5) * 8192 + (w + 4) * 1024 + l * 16);
    const half8 b0 =
        *(const half8*)(Eb + (size_t)(l & 15) * SL + n0 + (l >> 4) * 8);
    acc[0] = __builtin_amdgcn_mfma_f32_16x16x32_f16(a0, b0, acc[0], 0, 0, 0);
    acc[1] = __builtin_amdgcn_mfma_f32_16x16x32_f16(a1, b0, acc[1], 0, 0, 0);
  }
#pragma unroll
  for (int sv2 = 0; sv2 < 2; ++sv2) {
    const int q = l & 15;
    const int row = (w + sv2 * 4) * 16 + (l >> 4) * 4;
    *(f32x4*)&dst[(size_t)q * DH + row] = acc[sv2];
  }
}

// ---------------------------------------------------------------------------
// Kernel G: per (b, 2 q):  T[v][k] = sum_n (E_n*V[n,v]) * K[n,k]  via MFMA.
// NO LDS, NO barriers: fragments are loaded global->register directly
// (layout is fragment-linear, so each read is a coalesced 1KB wave load;
// A/B duplication across waves served by L1).  Explicit ping-pong prefetch
// distance 1; compiler inserts counted vmcnt (no barrier to drain them).
// out = scale*invd*(T - invd*EV[v]*EK[k]).
// ---------------------------------------------------------------------------
__global__ __launch_bounds__(256, 2) void kjac(
    const f16* __restrict__ Vt, const f16* __restrict__ Kt,
    const f16* __restrict__ E, const float* __restrict__ EV,
    const float* __restrict__ EK, const float* __restrict__ denom,
    float* __restrict__ out) {
  const int blk = (blockIdx.x & 7) * 64 + (blockIdx.x >> 3);  // XCD swizzle
  const int b = blk >> 5;
  const int q0 = (blk & 31) * 2;
  const int t = threadIdx.x, w = t >> 6, l = t & 63;
  const int sA = (w >> 1) * 4;  // A row-subtile base (quadrant)
  const int sB = (w & 1) * 4;   // B col-subtile base
  const char* vtb = (const char*)(Vt + (size_t)b * DH * SL) + sA * 1024 + l * 16;
  const char* ktb = (const char*)(Kt + (size_t)b * DH * SL) + sB * 1024 + l * 16;
  const f16* Eb = E + ((size_t)b * NQ + q0) * SL + (l >> 4) * 8;

  f32x4 acc[2][4][4] = {};
  half8 vfA[4], kfA[4], efA[2], vfB[4], kfB[4], efB[2];

#define LOADF(vf, kf, ef, tile)                                              \
  {                                                                          \
    const size_t gb = (size_t)(tile) * 8192;                                 \
    _Pragma("unroll") for (int i = 0; i < 4; ++i) vf[i] =                    \
        *(const half8*)(vtb + gb + i * 1024);                                \
    _Pragma("unroll") for (int j = 0; j < 4; ++j) kf[j] =                    \
        *(const half8*)(ktb + gb + j * 1024);                                \
    ef[0] = *(const half8*)(Eb + (tile) * 32);                               \
    ef[1] = *(const half8*)(Eb + SL + (tile) * 32);                          \
  }

#define MFMA32(vf, kf, ef)                                                   \
  {                                                                          \
    __builtin_amdgcn_s_setprio(1);                                           \
    _Pragma("unroll") for (int i = 0; i < 4; ++i) {                          \
      const half8 u0 = ef[0] * vf[i];                                        \
      const half8 u1 = ef[1] * vf[i];                                        \
      _Pragma("unroll") for (int j = 0; j < 4; ++j) {                        \
        acc[0][i][j] = __builtin_amdgcn_mfma_f32_16x16x32_f16(               \
            u0, kf[j], acc[0][i][j], 0, 0, 0);                               \
        acc[1][i][j] = __builtin_amdgcn_mfma_f32_16x16x32_f16(               \
            u1, kf[j], acc[1][i][j], 0, 0, 0);                               \
      }                                                                      \
    }                                                                        \
    __builtin_amdgcn_s_setprio(0);                                           \
  }

  LOADF(vfA, kfA, efA, 0)
  for (int tt = 0; tt < 126; tt += 2) {
    LOADF(vfB, kfB, efB, tt + 1)
    MFMA32(vfA, kfA, efA)
    LOADF(vfA, kfA, efA, tt + 2)
    MFMA32(vfB, kfB, efB)
  }
  LOADF(vfB, kfB, efB, 127)
  MFMA32(vfA, kfA, efA)
  MFMA32(vfB, kfB, efB)
#undef LOADF
#undef MFMA32

  const float scl = 0.08838834764831845f;
#pragma unroll
  for (int q = 0; q < 2; ++q) {
    const float invd = 1.0f / denom[b * NQ + q0 + q];
    const float* evq = EV + ((size_t)b * NQ + q0 + q) * DH;
    const float* evq2 = evq + (size_t)BATCH * NQ * DH;
    const float* ekq = EK + ((size_t)b * NQ + q0 + q) * DH;
    const float* ekq2 = ekq + (size_t)BATCH * NQ * DH;
    float* ob = out + (size_t)(b * NQ + q0 + q) * DH * DH;
#pragma unroll
    for (int i = 0; i < 4; ++i) {
      const int row0 = (sA + i) * 16 + (l >> 4) * 4;
      const f32x4 ev4 = *(const f32x4*)&evq[row0] + *(const f32x4*)&evq2[row0];
#pragma unroll
      for (int j = 0; j < 4; ++j) {
        const int col = (sB + j) * 16 + (l & 15);
        const float ek = ekq[col] + ekq2[col];
#pragma unroll
        for (int r = 0; r < 4; ++r)
          ob[(size_t)(row0 + r) * DH + col] =
              scl * invd * (acc[q][i][j][r] - invd * ev4[r] * ek);
      }
    }
  }
}

extern "C" void kernel_launch(void* const* d_in, const int* in_sizes, int n_in,
                              void* d_out, int out_size, void* d_ws,
                              size_t ws_size, hipStream_t stream) {
  const float* Q = (const float*)d_in[0];
  const float* K = (const float*)d_in[1];
  const float* V = (const float*)d_in[2];
  float* out = (float*)d_out;

  // ws: Vt 16.8MB | Kt 16.8MB | E f16 8.4MB | EVp 1MB | EKp 1MB | denom 4KB
  f16* Vt = (f16*)d_ws;
  f16* Kt = Vt + (size_t)BATCH * DH * SL;
  f16* Ef = Kt + (size_t)BATCH * DH * SL;
  float* EV = (float*)(Ef + (size_t)BATCH * NQ * SL);
  float* EK = EV + 2 * (size_t)BATCH * NQ * DH;
  float* denom = EK + 2 * (size_t)BATCH * NQ * DH;

  kprep<<<1024, 256, 0, stream>>>(K, V, Kt, Vt);
  kscore<<<512, 256, 0, stream>>>(Q, Kt, Ef);
  kreduce<<<256, 256, 0, stream>>>(Ef, denom);
  kev<<<256, 256, 0, stream>>>(Vt, Kt, Ef, EV, EK);
  kjac<<<512, 256, 0, stream>>>(Vt, Kt, Ef, EV, EK, denom, out);
}